// Round 9
// baseline (524.679 us; speedup 1.0000x reference)
//
#include <hip/hip_runtime.h>
#include <hip/hip_fp16.h>

#define NN 262144   // nodes
#define NE 1048576  // edges
#define NG 8192     // graphs
#define FD 64       // feature dim
#define AD 8        // adduct dim
#define DN 512      // dense dim

// ---------------- CSR build ----------------
__global__ void k_count(const int* __restrict__ dst, int* __restrict__ counts,
                        int* __restrict__ rank) {
  int e = blockIdx.x * 256 + threadIdx.x;
  rank[e] = atomicAdd(&counts[dst[e]], 1);
}

__global__ void k_scan1(const int* __restrict__ counts, int* __restrict__ rp,
                        int* __restrict__ bsum) {
  __shared__ int s[256];
  int tid = threadIdx.x;
  int i = blockIdx.x * 256 + tid;
  int orig = counts[i];
  s[tid] = orig;
  __syncthreads();
  for (int off = 1; off < 256; off <<= 1) {
    int v = (tid >= off) ? s[tid - off] : 0;
    __syncthreads();
    s[tid] += v;
    __syncthreads();
  }
  rp[i] = s[tid] - orig;  // block-local exclusive scan
  if (tid == 255) bsum[blockIdx.x] = s[tid];
}

__global__ void k_scan2(int* __restrict__ bsum) {
  __shared__ int s[1024];
  int tid = threadIdx.x;
  int orig = bsum[tid];
  s[tid] = orig;
  __syncthreads();
  for (int off = 1; off < 1024; off <<= 1) {
    int v = (tid >= off) ? s[tid - off] : 0;
    __syncthreads();
    s[tid] += v;
    __syncthreads();
  }
  bsum[tid] = s[tid] - orig;  // exclusive
}

__global__ void k_scan3(const int* __restrict__ counts, int* __restrict__ rp,
                        const int* __restrict__ bsum, float* __restrict__ rsq) {
  int i = blockIdx.x * 256 + threadIdx.x;
  rp[i] = rp[i] + bsum[blockIdx.x];
  rsq[i] = rsqrtf((float)(counts[i] + 1));
  if (i == 0) rp[NN] = NE;
}

// Atomic-free XCD-partitioned scatter (validated R14). Plain src payload.
#define FILL_EPT 16
#define FILL_CHUNK (256 * FILL_EPT)
__global__ void k_fill(const int* __restrict__ src, const int* __restrict__ dst,
                       const int* __restrict__ rank, const int* __restrict__ rp,
                       int* __restrict__ csr_s) {
  int xcd = blockIdx.x & 7;
  int chunk = blockIdx.x >> 3;
  int base = chunk * FILL_CHUNK + threadIdx.x;
#pragma unroll
  for (int i = 0; i < FILL_EPT; i++) {
    int e = base + i * 256;
    int d = dst[e];
    if ((d >> 15) == xcd) {
      csr_s[rp[d] + rank[e]] = src[e];
    }
  }
}

// ---------------- fp16 row helpers (R19, validated) ----------------
__device__ __forceinline__ float4 ldrow_h(const uint2* __restrict__ th2,
                                          size_t n, int ln) {
  uint2 u = th2[n * 16 + ln];
  __half2 p0 = *reinterpret_cast<__half2*>(&u.x);
  __half2 p1 = *reinterpret_cast<__half2*>(&u.y);
  float2 f0 = __half22float2(p0);
  float2 f1 = __half22float2(p1);
  return make_float4(f0.x, f0.y, f1.x, f1.y);
}

__device__ __forceinline__ void strow_h(uint2* __restrict__ th2, size_t idx,
                                        float x, float y, float z, float w) {
  __half2 p0 = __floats2half2_rn(x, y);
  __half2 p1 = __floats2half2_rn(z, w);
  uint2 u;
  u.x = *reinterpret_cast<unsigned int*>(&p0);
  u.y = *reinterpret_cast<unsigned int*>(&p1);
  th2[idx] = u;
}

// ---------------- GCN layer 1: t' = (x @ W + b) * rsq[n]  (fp16 out) ------
#define HS 68  // row stride (floats): 272 B, 16B-aligned, breaks pow2 banks
__global__ void __launch_bounds__(256) k_transform(const float* __restrict__ hin,
                                                   const float* __restrict__ W,
                                                   const float* __restrict__ b,
                                                   const float* __restrict__ rsq,
                                                   uint2* __restrict__ tout) {
  __shared__ float hsT[64 * HS];  // [k][n]  17.4 KB
  int tid = threadIdx.x;
  size_t base = (size_t)blockIdx.x * 64 * 64;

  const float4* h4 = (const float4*)(hin + base);
#pragma unroll
  for (int j = 0; j < 4; j++) {
    int f = tid + 256 * j;
    int n = f >> 4, kq = f & 15;
    float4 v = h4[f];
    hsT[(4 * kq + 0) * HS + n] = v.x;
    hsT[(4 * kq + 1) * HS + n] = v.y;
    hsT[(4 * kq + 2) * HS + n] = v.z;
    hsT[(4 * kq + 3) * HS + n] = v.w;
  }
  __syncthreads();

  int n0 = (tid >> 4) * 4;
  int c0 = (tid & 15) * 4;
  float acc[4][4];
#pragma unroll
  for (int i = 0; i < 4; i++)
#pragma unroll
    for (int j = 0; j < 4; j++) acc[i][j] = b[c0 + j];

#pragma unroll 4
  for (int k = 0; k < 64; k++) {
    float4 av = *(const float4*)&hsT[k * HS + n0];   // ds_read_b128
    float4 bv = *(const float4*)&W[k * 64 + c0];     // global, L1-hit broadcast
    acc[0][0] = fmaf(av.x, bv.x, acc[0][0]);
    acc[0][1] = fmaf(av.x, bv.y, acc[0][1]);
    acc[0][2] = fmaf(av.x, bv.z, acc[0][2]);
    acc[0][3] = fmaf(av.x, bv.w, acc[0][3]);
    acc[1][0] = fmaf(av.y, bv.x, acc[1][0]);
    acc[1][1] = fmaf(av.y, bv.y, acc[1][1]);
    acc[1][2] = fmaf(av.y, bv.z, acc[1][2]);
    acc[1][3] = fmaf(av.y, bv.w, acc[1][3]);
    acc[2][0] = fmaf(av.z, bv.x, acc[2][0]);
    acc[2][1] = fmaf(av.z, bv.y, acc[2][1]);
    acc[2][2] = fmaf(av.z, bv.z, acc[2][2]);
    acc[2][3] = fmaf(av.z, bv.w, acc[2][3]);
    acc[3][0] = fmaf(av.w, bv.x, acc[3][0]);
    acc[3][1] = fmaf(av.w, bv.y, acc[3][1]);
    acc[3][2] = fmaf(av.w, bv.z, acc[3][2]);
    acc[3][3] = fmaf(av.w, bv.w, acc[3][3]);
  }

  int nbase = blockIdx.x * 64;
#pragma unroll
  for (int i = 0; i < 4; i++) {
    float rs = rsq[nbase + n0 + i];
    strow_h(tout, (size_t)(nbase + n0 + i) * 16 + (c0 >> 2),
            acc[i][0] * rs, acc[i][1] * rs, acc[i][2] * rs, acc[i][3] * rs);
  }
}

// ---------------- aggregation core (R16 engine, fp16 gather) ----------------
__device__ __forceinline__ void aggregate_nodes(const uint2* __restrict__ th2,
                                                const int* __restrict__ rp,
                                                const int* __restrict__ csr_s,
                                                const float* __restrict__ rsq,
                                                float* __restrict__ hacc,
                                                int nbase, int grp, int ln) {
  for (int r = 0; r < 4; r++) {
    int n = nbase + r * 16 + grp;
    int beg = rp[n], end = rp[n + 1];
    float rn = rsq[n];
    float4 a0 = ldrow_h(th2, (size_t)n, ln);  // self term t'[n]
    float4 a1 = make_float4(0.f, 0.f, 0.f, 0.f);
    float4 a2 = make_float4(0.f, 0.f, 0.f, 0.f);
    float4 a3 = make_float4(0.f, 0.f, 0.f, 0.f);

    int idx = beg;
    for (; idx + 4 <= end; idx += 4) {
      int s0 = csr_s[idx + 0];
      int s1 = csr_s[idx + 1];
      int s2 = csr_s[idx + 2];
      int s3 = csr_s[idx + 3];
      float4 v0 = ldrow_h(th2, (size_t)s0, ln);
      float4 v1 = ldrow_h(th2, (size_t)s1, ln);
      float4 v2 = ldrow_h(th2, (size_t)s2, ln);
      float4 v3 = ldrow_h(th2, (size_t)s3, ln);
      a0.x += v0.x; a0.y += v0.y; a0.z += v0.z; a0.w += v0.w;
      a1.x += v1.x; a1.y += v1.y; a1.z += v1.z; a1.w += v1.w;
      a2.x += v2.x; a2.y += v2.y; a2.z += v2.z; a2.w += v2.w;
      a3.x += v3.x; a3.y += v3.y; a3.z += v3.z; a3.w += v3.w;
    }
    if (idx + 2 <= end) {
      int s0 = csr_s[idx + 0];
      int s1 = csr_s[idx + 1];
      float4 v0 = ldrow_h(th2, (size_t)s0, ln);
      float4 v1 = ldrow_h(th2, (size_t)s1, ln);
      a0.x += v0.x; a0.y += v0.y; a0.z += v0.z; a0.w += v0.w;
      a1.x += v1.x; a1.y += v1.y; a1.z += v1.z; a1.w += v1.w;
      idx += 2;
    }
    if (idx < end) {
      int s0 = csr_s[idx];
      float4 v0 = ldrow_h(th2, (size_t)s0, ln);
      a0.x += v0.x; a0.y += v0.y; a0.z += v0.z; a0.w += v0.w;
    }
    int nl = r * 16 + grp;
    float4 v;
    v.x = fmaxf(rn * ((a0.x + a1.x) + (a2.x + a3.x)), 0.f);
    v.y = fmaxf(rn * ((a0.y + a1.y) + (a2.y + a3.y)), 0.f);
    v.z = fmaxf(rn * ((a0.z + a1.z) + (a2.z + a3.z)), 0.f);
    v.w = fmaxf(rn * ((a0.w + a1.w) + (a2.w + a3.w)), 0.f);
    *(float4*)&hacc[nl * HS + 4 * ln] = v;  // 2-way wrap -> conflict-free
  }
}

// Fused aggregate + next-layer transform (h never touches HBM).
__global__ void __launch_bounds__(256) k_aggT(const uint2* __restrict__ tin,
                                              const int* __restrict__ rp,
                                              const int* __restrict__ csr_s,
                                              const float* __restrict__ rsq,
                                              const float* __restrict__ W,
                                              const float* __restrict__ b,
                                              uint2* __restrict__ tout) {
  __shared__ float hacc[64 * HS];  // [n][k] h' tile, 17.4 KB
  int tid = threadIdx.x;
  int grp = tid >> 4;
  int ln = tid & 15;
  int nbase = blockIdx.x * 64;

  aggregate_nodes(tin, rp, csr_s, rsq, hacc, nbase, grp, ln);
  __syncthreads();

  // GEMM: tout[n][c] = (h'[n][:] @ W + b) * rsq[n]
  int n0 = (tid >> 4) * 4;
  int c0 = (tid & 15) * 4;
  float acc[4][4];
#pragma unroll
  for (int i = 0; i < 4; i++)
#pragma unroll
    for (int j = 0; j < 4; j++) acc[i][j] = b[c0 + j];

#pragma unroll 4
  for (int k = 0; k < 64; k++) {
    float a0 = hacc[(n0 + 0) * HS + k];  // same-addr broadcast per quarter-wave
    float a1 = hacc[(n0 + 1) * HS + k];
    float a2 = hacc[(n0 + 2) * HS + k];
    float a3 = hacc[(n0 + 3) * HS + k];
    float4 bv = *(const float4*)&W[k * 64 + c0];  // global, L1-hit
    acc[0][0] = fmaf(a0, bv.x, acc[0][0]);
    acc[0][1] = fmaf(a0, bv.y, acc[0][1]);
    acc[0][2] = fmaf(a0, bv.z, acc[0][2]);
    acc[0][3] = fmaf(a0, bv.w, acc[0][3]);
    acc[1][0] = fmaf(a1, bv.x, acc[1][0]);
    acc[1][1] = fmaf(a1, bv.y, acc[1][1]);
    acc[1][2] = fmaf(a1, bv.z, acc[1][2]);
    acc[1][3] = fmaf(a1, bv.w, acc[1][3]);
    acc[2][0] = fmaf(a2, bv.x, acc[2][0]);
    acc[2][1] = fmaf(a2, bv.y, acc[2][1]);
    acc[2][2] = fmaf(a2, bv.z, acc[2][2]);
    acc[2][3] = fmaf(a2, bv.w, acc[2][3]);
    acc[3][0] = fmaf(a3, bv.x, acc[3][0]);
    acc[3][1] = fmaf(a3, bv.y, acc[3][1]);
    acc[3][2] = fmaf(a3, bv.z, acc[3][2]);
    acc[3][3] = fmaf(a3, bv.w, acc[3][3]);
  }

#pragma unroll
  for (int i = 0; i < 4; i++) {
    float rs = rsq[nbase + n0 + i];
    strow_h(tout, (size_t)(nbase + n0 + i) * 16 + (c0 >> 2),
            acc[i][0] * rs, acc[i][1] * rs, acc[i][2] * rs, acc[i][3] * rs);
  }
}

// ---------------- R18: fused final aggregate + readout ----------------
__global__ void __launch_bounds__(256) k_aggR(const uint2* __restrict__ tin,
                                              const int* __restrict__ rp,
                                              const int* __restrict__ csr_s,
                                              const float* __restrict__ rsq,
                                              const int* __restrict__ gids,
                                              float* __restrict__ r) {
  __shared__ float hacc[64 * HS];
  __shared__ int gl[64];
  int tid = threadIdx.x;
  int grp = tid >> 4;
  int ln = tid & 15;
  int nbase = blockIdx.x * 64;
  if (tid < 64) gl[tid] = gids[nbase + tid];

  aggregate_nodes(tin, rp, csr_s, rsq, hacc, nbase, grp, ln);
  __syncthreads();

  // Segmented reduce: wave w handles rows [w*16, w*16+16), lane = column.
  int c = tid & 63;
  int row0 = (tid >> 6) * 16;
  int cur = gl[row0];
  float run = 0.f;
  for (int rr = 0; rr < 16; rr++) {
    int g = gl[row0 + rr];
    float v = hacc[(row0 + rr) * HS + c];
    if (g != cur) {
      atomicAdd(&r[(size_t)cur * 64 + c], run);
      cur = g;
      run = v;
    } else {
      run += v;
    }
  }
  atomicAdd(&r[(size_t)cur * 64 + c], run);
}

// ---------------- Dense head ----------------
__global__ void __launch_bounds__(256) k_dense1(const float* __restrict__ r,
                                                const float* __restrict__ xa,
                                                const float* __restrict__ W1,
                                                const float* __restrict__ b1,
                                                const float* __restrict__ ob,
                                                float* __restrict__ out,
                                                float* __restrict__ y1T) {
  __shared__ float xs[8 * 72];
  int tid = threadIdx.x;
  int g0 = blockIdx.x * 8;
  if (tid < 8) out[g0 + tid] = ob[0];
  for (int i = tid; i < 8 * 72; i += 256) {
    int g = i / 72, k = i % 72;
    xs[i] = (k < 64) ? r[(size_t)(g0 + g) * 64 + k] : xa[(size_t)(g0 + g) * 8 + (k - 64)];
  }
  __syncthreads();
  float acc[8][2];
#pragma unroll
  for (int g = 0; g < 8; g++) { acc[g][0] = 0.f; acc[g][1] = 0.f; }
  for (int k = 0; k < 72; k++) {
    float w0 = W1[k * 512 + tid];
    float w1 = W1[k * 512 + 256 + tid];
#pragma unroll
    for (int g = 0; g < 8; g++) {
      float xv = xs[g * 72 + k];
      acc[g][0] = fmaf(xv, w0, acc[g][0]);
      acc[g][1] = fmaf(xv, w1, acc[g][1]);
    }
  }
  float bb0 = b1[tid], bb1 = b1[256 + tid];
  float4 v;
  v = make_float4(fmaxf(acc[0][0] + bb0, 0.f), fmaxf(acc[1][0] + bb0, 0.f),
                  fmaxf(acc[2][0] + bb0, 0.f), fmaxf(acc[3][0] + bb0, 0.f));
  *(float4*)&y1T[(size_t)tid * NG + g0] = v;
  v = make_float4(fmaxf(acc[4][0] + bb0, 0.f), fmaxf(acc[5][0] + bb0, 0.f),
                  fmaxf(acc[6][0] + bb0, 0.f), fmaxf(acc[7][0] + bb0, 0.f));
  *(float4*)&y1T[(size_t)tid * NG + g0 + 4] = v;
  v = make_float4(fmaxf(acc[0][1] + bb1, 0.f), fmaxf(acc[1][1] + bb1, 0.f),
                  fmaxf(acc[2][1] + bb1, 0.f), fmaxf(acc[3][1] + bb1, 0.f));
  *(float4*)&y1T[(size_t)(256 + tid) * NG + g0] = v;
  v = make_float4(fmaxf(acc[4][1] + bb1, 0.f), fmaxf(acc[5][1] + bb1, 0.f),
                  fmaxf(acc[6][1] + bb1, 0.f), fmaxf(acc[7][1] + bb1, 0.f));
  *(float4*)&y1T[(size_t)(256 + tid) * NG + g0 + 4] = v;
}

// R21: dense2 with W2 through the SCALAR path. R20 post-mortem: W2-from-
// global-vector regressed (each lane's redundant dwordx4 eats TA/L1 BW).
// Remap: wave = 16-j block (readfirstlane -> SGPR, s_load broadcast),
// lane = g column (owns g, g+64). Per k per thread: 2 stride-1 ds_read_b32
// (2 lanes/bank = free) + 16 scalar W floats + 32 FMA -> FMA-bound
// (~27 us floor vs 62 us LDS floor of the R19 version).
#define DBK 32
__global__ void __launch_bounds__(512) k_dense2(const float* __restrict__ xT,
                                                const float* __restrict__ W2,
                                                const float* __restrict__ b2,
                                                const float* __restrict__ ow,
                                                float* __restrict__ out) {
  __shared__ float xs[DBK * 128];  // [k][g] 16 KB (x only; W2 scalar)
  __shared__ float po[128];
  int tid = threadIdx.x;  // 512
  int g0 = (blockIdx.x & 63) * 128;
  int j0 = (blockIdx.x >> 6) * 128;
  int gl = tid & 63;                                   // lane: g column
  int wv = __builtin_amdgcn_readfirstlane(tid >> 6);   // wave: j-block (SGPR)
  const float* Wj  = W2 + j0 + wv * 16;  // uniform base -> s_load path
  const float* bj  = b2 + j0 + wv * 16;
  const float* owj = ow + j0 + wv * 16;

  float acc[16][2];  // [j][g]
#pragma unroll
  for (int jj = 0; jj < 16; jj++) {
    float bb = bj[jj];  // scalar
    acc[jj][0] = bb;
    acc[jj][1] = bb;
  }

  // x staging (R20-validated reg prefetch): f=tid -> kr=tid>>5, gc=tid&31;
  // f=tid+512 -> kr+16, same gc.
  int kr0 = tid >> 5, gc0 = tid & 31;
  float4 r0 = ((const float4*)(xT + (size_t)kr0 * NG + g0))[gc0];
  float4 r1 = ((const float4*)(xT + (size_t)(kr0 + 16) * NG + g0))[gc0];

  for (int kb = 0; kb < 512; kb += DBK) {
    __syncthreads();
    ((float4*)xs)[tid] = r0;
    ((float4*)xs)[tid + 512] = r1;
    if (kb + DBK < 512) {
      r0 = ((const float4*)(xT + (size_t)(kb + DBK + kr0) * NG + g0))[gc0];
      r1 = ((const float4*)(xT + (size_t)(kb + DBK + kr0 + 16) * NG + g0))[gc0];
    }
    __syncthreads();
#pragma unroll 4
    for (int k = 0; k < DBK; k++) {
      float x0 = xs[k * 128 + gl];        // stride-1 across lanes: conflict-free
      float x1 = xs[k * 128 + 64 + gl];
      const float* wrow = Wj + (size_t)(kb + k) * 512;
#pragma unroll
      for (int jj = 0; jj < 16; jj++) {
        float w = wrow[jj];               // wave-uniform -> SGPR broadcast
        acc[jj][0] = fmaf(w, x0, acc[jj][0]);
        acc[jj][1] = fmaf(w, x1, acc[jj][1]);
      }
    }
  }

  // fused out-epilogue: per-thread partial dot over its 16 j, then LDS
  // atomics across the 8 waves, then one global atomic per g.
  if (tid < 128) po[tid] = 0.f;
  __syncthreads();
  float pv0 = 0.f, pv1 = 0.f;
#pragma unroll
  for (int jj = 0; jj < 16; jj++) {
    float w = owj[jj];  // scalar
    pv0 = fmaf(fmaxf(acc[jj][0], 0.f), w, pv0);
    pv1 = fmaf(fmaxf(acc[jj][1], 0.f), w, pv1);
  }
  atomicAdd(&po[gl], pv0);
  atomicAdd(&po[64 + gl], pv1);
  __syncthreads();
  if (tid < 128) atomicAdd(&out[g0 + tid], po[tid]);
}

extern "C" void kernel_launch(void* const* d_in, const int* in_sizes, int n_in,
                              void* d_out, int out_size, void* d_ws, size_t ws_size,
                              hipStream_t stream) {
  const float* x_mol    = (const float*)d_in[0];
  const float* x_adduct = (const float*)d_in[1];
  const int*   edge_src = (const int*)d_in[2];
  const int*   edge_dst = (const int*)d_in[3];
  const int*   graph_ids= (const int*)d_in[4];
  const float* gcn_W    = (const float*)d_in[5];
  const float* gcn_b    = (const float*)d_in[6];
  const float* d1W      = (const float*)d_in[7];
  const float* d1b      = (const float*)d_in[8];
  const float* d2W      = (const float*)d_in[9];
  const float* d2b      = (const float*)d_in[10];
  const float* oW       = (const float*)d_in[11];
  const float* obias    = (const float*)d_in[12];
  float* out = (float*)d_out;

  char* p = (char*)d_ws;
  auto alloc = [&](size_t bytes) {
    char* q = p;
    p += (bytes + 255) & ~(size_t)255;
    return q;
  };
  int*   counts   = (int*)alloc((size_t)NN * 4);
  int*   rp       = (int*)alloc((size_t)(NN + 1) * 4);
  int*   bsum     = (int*)alloc(1024 * 4);
  float* rsq      = (float*)alloc((size_t)NN * 4);
  int*   rank     = (int*)alloc((size_t)NE * 4);
  int*   csr_s    = (int*)alloc((size_t)NE * 4);
  uint2* th_a     = (uint2*)alloc((size_t)NN * 64 * 2);  // fp16 t rows (32 MB)
  uint2* th_b     = (uint2*)alloc((size_t)NN * 64 * 2);
  float* r        = (float*)alloc((size_t)NG * 64 * 4);
  float* y1T      = (float*)alloc((size_t)NG * 512 * 4);

  hipMemsetAsync(counts, 0, (size_t)NN * 4, stream);
  hipMemsetAsync(r, 0, (size_t)NG * 64 * 4, stream);
  k_count<<<NE / 256, 256, 0, stream>>>(edge_dst, counts, rank);
  k_scan1<<<NN / 256, 256, 0, stream>>>(counts, rp, bsum);
  k_scan2<<<1, 1024, 0, stream>>>(bsum);
  k_scan3<<<NN / 256, 256, 0, stream>>>(counts, rp, bsum, rsq);
  k_fill<<<8 * (NE / FILL_CHUNK), 256, 0, stream>>>(edge_src, edge_dst, rank, rp, csr_s);

  // t1 = transform(x_mol); t2 = aggT(t1); t3 = aggT(t2); r = aggR(t3)
  k_transform<<<NN / 64, 256, 0, stream>>>(x_mol, gcn_W, gcn_b, rsq, th_a);
  k_aggT<<<NN / 64, 256, 0, stream>>>(th_a, rp, csr_s, rsq,
                                      gcn_W + (size_t)1 * 64 * 64,
                                      gcn_b + (size_t)1 * 64, th_b);
  k_aggT<<<NN / 64, 256, 0, stream>>>(th_b, rp, csr_s, rsq,
                                      gcn_W + (size_t)2 * 64 * 64,
                                      gcn_b + (size_t)2 * 64, th_a);
  k_aggR<<<NN / 64, 256, 0, stream>>>(th_a, rp, csr_s, rsq, graph_ids, r);

  k_dense1<<<NG / 8, 256, 0, stream>>>(r, x_adduct, d1W, d1b, obias, out, y1T);
  k_dense2<<<256, 512, 0, stream>>>(y1T, d2W, d2b, oW, out);
}

// Round 10
// 470.102 us; speedup vs baseline: 1.1161x; 1.1161x over previous
//
#include <hip/hip_runtime.h>
#include <hip/hip_fp16.h>

#define NN 262144   // nodes
#define NE 1048576  // edges
#define NG 8192     // graphs
#define FD 64       // feature dim
#define AD 8        // adduct dim
#define DN 512      // dense dim

// ---------------- CSR build ----------------
__global__ void k_count(const int* __restrict__ dst, int* __restrict__ counts,
                        int* __restrict__ rank) {
  int e = blockIdx.x * 256 + threadIdx.x;
  rank[e] = atomicAdd(&counts[dst[e]], 1);
}

__global__ void k_scan1(const int* __restrict__ counts, int* __restrict__ rp,
                        int* __restrict__ bsum) {
  __shared__ int s[256];
  int tid = threadIdx.x;
  int i = blockIdx.x * 256 + tid;
  int orig = counts[i];
  s[tid] = orig;
  __syncthreads();
  for (int off = 1; off < 256; off <<= 1) {
    int v = (tid >= off) ? s[tid - off] : 0;
    __syncthreads();
    s[tid] += v;
    __syncthreads();
  }
  rp[i] = s[tid] - orig;  // block-local exclusive scan
  if (tid == 255) bsum[blockIdx.x] = s[tid];
}

__global__ void k_scan2(int* __restrict__ bsum) {
  __shared__ int s[1024];
  int tid = threadIdx.x;
  int orig = bsum[tid];
  s[tid] = orig;
  __syncthreads();
  for (int off = 1; off < 1024; off <<= 1) {
    int v = (tid >= off) ? s[tid - off] : 0;
    __syncthreads();
    s[tid] += v;
    __syncthreads();
  }
  bsum[tid] = s[tid] - orig;  // exclusive
}

__global__ void k_scan3(const int* __restrict__ counts, int* __restrict__ rp,
                        const int* __restrict__ bsum, float* __restrict__ rsq) {
  int i = blockIdx.x * 256 + threadIdx.x;
  rp[i] = rp[i] + bsum[blockIdx.x];
  rsq[i] = rsqrtf((float)(counts[i] + 1));
  if (i == 0) rp[NN] = NE;
}

// Atomic-free XCD-partitioned scatter (validated R14). Plain src payload.
#define FILL_EPT 16
#define FILL_CHUNK (256 * FILL_EPT)
__global__ void k_fill(const int* __restrict__ src, const int* __restrict__ dst,
                       const int* __restrict__ rank, const int* __restrict__ rp,
                       int* __restrict__ csr_s) {
  int xcd = blockIdx.x & 7;
  int chunk = blockIdx.x >> 3;
  int base = chunk * FILL_CHUNK + threadIdx.x;
#pragma unroll
  for (int i = 0; i < FILL_EPT; i++) {
    int e = base + i * 256;
    int d = dst[e];
    if ((d >> 15) == xcd) {
      csr_s[rp[d] + rank[e]] = src[e];
    }
  }
}

// ---------------- fp16 row helpers (R19, validated) ----------------
__device__ __forceinline__ float4 ldrow_h(const uint2* __restrict__ th2,
                                          size_t n, int ln) {
  uint2 u = th2[n * 16 + ln];
  __half2 p0 = *reinterpret_cast<__half2*>(&u.x);
  __half2 p1 = *reinterpret_cast<__half2*>(&u.y);
  float2 f0 = __half22float2(p0);
  float2 f1 = __half22float2(p1);
  return make_float4(f0.x, f0.y, f1.x, f1.y);
}

__device__ __forceinline__ void strow_h(uint2* __restrict__ th2, size_t idx,
                                        float x, float y, float z, float w) {
  __half2 p0 = __floats2half2_rn(x, y);
  __half2 p1 = __floats2half2_rn(z, w);
  uint2 u;
  u.x = *reinterpret_cast<unsigned int*>(&p0);
  u.y = *reinterpret_cast<unsigned int*>(&p1);
  th2[idx] = u;
}

// ---------------- GCN layer 1: t' = (x @ W + b) * rsq[n]  (fp16 out) ------
#define HS 68  // row stride (floats): 272 B, 16B-aligned, breaks pow2 banks
__global__ void __launch_bounds__(256) k_transform(const float* __restrict__ hin,
                                                   const float* __restrict__ W,
                                                   const float* __restrict__ b,
                                                   const float* __restrict__ rsq,
                                                   uint2* __restrict__ tout) {
  __shared__ float hsT[64 * HS];  // [k][n]  17.4 KB
  int tid = threadIdx.x;
  size_t base = (size_t)blockIdx.x * 64 * 64;

  const float4* h4 = (const float4*)(hin + base);
#pragma unroll
  for (int j = 0; j < 4; j++) {
    int f = tid + 256 * j;
    int n = f >> 4, kq = f & 15;
    float4 v = h4[f];
    hsT[(4 * kq + 0) * HS + n] = v.x;
    hsT[(4 * kq + 1) * HS + n] = v.y;
    hsT[(4 * kq + 2) * HS + n] = v.z;
    hsT[(4 * kq + 3) * HS + n] = v.w;
  }
  __syncthreads();

  int n0 = (tid >> 4) * 4;
  int c0 = (tid & 15) * 4;
  float acc[4][4];
#pragma unroll
  for (int i = 0; i < 4; i++)
#pragma unroll
    for (int j = 0; j < 4; j++) acc[i][j] = b[c0 + j];

#pragma unroll 4
  for (int k = 0; k < 64; k++) {
    float4 av = *(const float4*)&hsT[k * HS + n0];   // ds_read_b128
    float4 bv = *(const float4*)&W[k * 64 + c0];     // global, L1-hit broadcast
    acc[0][0] = fmaf(av.x, bv.x, acc[0][0]);
    acc[0][1] = fmaf(av.x, bv.y, acc[0][1]);
    acc[0][2] = fmaf(av.x, bv.z, acc[0][2]);
    acc[0][3] = fmaf(av.x, bv.w, acc[0][3]);
    acc[1][0] = fmaf(av.y, bv.x, acc[1][0]);
    acc[1][1] = fmaf(av.y, bv.y, acc[1][1]);
    acc[1][2] = fmaf(av.y, bv.z, acc[1][2]);
    acc[1][3] = fmaf(av.y, bv.w, acc[1][3]);
    acc[2][0] = fmaf(av.z, bv.x, acc[2][0]);
    acc[2][1] = fmaf(av.z, bv.y, acc[2][1]);
    acc[2][2] = fmaf(av.z, bv.z, acc[2][2]);
    acc[2][3] = fmaf(av.z, bv.w, acc[2][3]);
    acc[3][0] = fmaf(av.w, bv.x, acc[3][0]);
    acc[3][1] = fmaf(av.w, bv.y, acc[3][1]);
    acc[3][2] = fmaf(av.w, bv.z, acc[3][2]);
    acc[3][3] = fmaf(av.w, bv.w, acc[3][3]);
  }

  int nbase = blockIdx.x * 64;
#pragma unroll
  for (int i = 0; i < 4; i++) {
    float rs = rsq[nbase + n0 + i];
    strow_h(tout, (size_t)(nbase + n0 + i) * 16 + (c0 >> 2),
            acc[i][0] * rs, acc[i][1] * rs, acc[i][2] * rs, acc[i][3] * rs);
  }
}

// ---------------- aggregation core (R16 engine, fp16 gather) ----------------
__device__ __forceinline__ void aggregate_nodes(const uint2* __restrict__ th2,
                                                const int* __restrict__ rp,
                                                const int* __restrict__ csr_s,
                                                const float* __restrict__ rsq,
                                                float* __restrict__ hacc,
                                                int nbase, int grp, int ln) {
  for (int r = 0; r < 4; r++) {
    int n = nbase + r * 16 + grp;
    int beg = rp[n], end = rp[n + 1];
    float rn = rsq[n];
    float4 a0 = ldrow_h(th2, (size_t)n, ln);  // self term t'[n]
    float4 a1 = make_float4(0.f, 0.f, 0.f, 0.f);
    float4 a2 = make_float4(0.f, 0.f, 0.f, 0.f);
    float4 a3 = make_float4(0.f, 0.f, 0.f, 0.f);

    int idx = beg;
    for (; idx + 4 <= end; idx += 4) {
      int s0 = csr_s[idx + 0];
      int s1 = csr_s[idx + 1];
      int s2 = csr_s[idx + 2];
      int s3 = csr_s[idx + 3];
      float4 v0 = ldrow_h(th2, (size_t)s0, ln);
      float4 v1 = ldrow_h(th2, (size_t)s1, ln);
      float4 v2 = ldrow_h(th2, (size_t)s2, ln);
      float4 v3 = ldrow_h(th2, (size_t)s3, ln);
      a0.x += v0.x; a0.y += v0.y; a0.z += v0.z; a0.w += v0.w;
      a1.x += v1.x; a1.y += v1.y; a1.z += v1.z; a1.w += v1.w;
      a2.x += v2.x; a2.y += v2.y; a2.z += v2.z; a2.w += v2.w;
      a3.x += v3.x; a3.y += v3.y; a3.z += v3.z; a3.w += v3.w;
    }
    if (idx + 2 <= end) {
      int s0 = csr_s[idx + 0];
      int s1 = csr_s[idx + 1];
      float4 v0 = ldrow_h(th2, (size_t)s0, ln);
      float4 v1 = ldrow_h(th2, (size_t)s1, ln);
      a0.x += v0.x; a0.y += v0.y; a0.z += v0.z; a0.w += v0.w;
      a1.x += v1.x; a1.y += v1.y; a1.z += v1.z; a1.w += v1.w;
      idx += 2;
    }
    if (idx < end) {
      int s0 = csr_s[idx];
      float4 v0 = ldrow_h(th2, (size_t)s0, ln);
      a0.x += v0.x; a0.y += v0.y; a0.z += v0.z; a0.w += v0.w;
    }
    int nl = r * 16 + grp;
    float4 v;
    v.x = fmaxf(rn * ((a0.x + a1.x) + (a2.x + a3.x)), 0.f);
    v.y = fmaxf(rn * ((a0.y + a1.y) + (a2.y + a3.y)), 0.f);
    v.z = fmaxf(rn * ((a0.z + a1.z) + (a2.z + a3.z)), 0.f);
    v.w = fmaxf(rn * ((a0.w + a1.w) + (a2.w + a3.w)), 0.f);
    *(float4*)&hacc[nl * HS + 4 * ln] = v;  // 2-way wrap -> conflict-free
  }
}

// Fused aggregate + next-layer transform (h never touches HBM).
__global__ void __launch_bounds__(256) k_aggT(const uint2* __restrict__ tin,
                                              const int* __restrict__ rp,
                                              const int* __restrict__ csr_s,
                                              const float* __restrict__ rsq,
                                              const float* __restrict__ W,
                                              const float* __restrict__ b,
                                              uint2* __restrict__ tout) {
  __shared__ float hacc[64 * HS];  // [n][k] h' tile, 17.4 KB
  int tid = threadIdx.x;
  int grp = tid >> 4;
  int ln = tid & 15;
  int nbase = blockIdx.x * 64;

  aggregate_nodes(tin, rp, csr_s, rsq, hacc, nbase, grp, ln);
  __syncthreads();

  // GEMM: tout[n][c] = (h'[n][:] @ W + b) * rsq[n]
  int n0 = (tid >> 4) * 4;
  int c0 = (tid & 15) * 4;
  float acc[4][4];
#pragma unroll
  for (int i = 0; i < 4; i++)
#pragma unroll
    for (int j = 0; j < 4; j++) acc[i][j] = b[c0 + j];

#pragma unroll 4
  for (int k = 0; k < 64; k++) {
    float a0 = hacc[(n0 + 0) * HS + k];  // same-addr broadcast per quarter-wave
    float a1 = hacc[(n0 + 1) * HS + k];
    float a2 = hacc[(n0 + 2) * HS + k];
    float a3 = hacc[(n0 + 3) * HS + k];
    float4 bv = *(const float4*)&W[k * 64 + c0];  // global, L1-hit
    acc[0][0] = fmaf(a0, bv.x, acc[0][0]);
    acc[0][1] = fmaf(a0, bv.y, acc[0][1]);
    acc[0][2] = fmaf(a0, bv.z, acc[0][2]);
    acc[0][3] = fmaf(a0, bv.w, acc[0][3]);
    acc[1][0] = fmaf(a1, bv.x, acc[1][0]);
    acc[1][1] = fmaf(a1, bv.y, acc[1][1]);
    acc[1][2] = fmaf(a1, bv.z, acc[1][2]);
    acc[1][3] = fmaf(a1, bv.w, acc[1][3]);
    acc[2][0] = fmaf(a2, bv.x, acc[2][0]);
    acc[2][1] = fmaf(a2, bv.y, acc[2][1]);
    acc[2][2] = fmaf(a2, bv.z, acc[2][2]);
    acc[2][3] = fmaf(a2, bv.w, acc[2][3]);
    acc[3][0] = fmaf(a3, bv.x, acc[3][0]);
    acc[3][1] = fmaf(a3, bv.y, acc[3][1]);
    acc[3][2] = fmaf(a3, bv.z, acc[3][2]);
    acc[3][3] = fmaf(a3, bv.w, acc[3][3]);
  }

#pragma unroll
  for (int i = 0; i < 4; i++) {
    float rs = rsq[nbase + n0 + i];
    strow_h(tout, (size_t)(nbase + n0 + i) * 16 + (c0 >> 2),
            acc[i][0] * rs, acc[i][1] * rs, acc[i][2] * rs, acc[i][3] * rs);
  }
}

// ---------------- R18: fused final aggregate + readout ----------------
__global__ void __launch_bounds__(256) k_aggR(const uint2* __restrict__ tin,
                                              const int* __restrict__ rp,
                                              const int* __restrict__ csr_s,
                                              const float* __restrict__ rsq,
                                              const int* __restrict__ gids,
                                              float* __restrict__ r) {
  __shared__ float hacc[64 * HS];
  __shared__ int gl[64];
  int tid = threadIdx.x;
  int grp = tid >> 4;
  int ln = tid & 15;
  int nbase = blockIdx.x * 64;
  if (tid < 64) gl[tid] = gids[nbase + tid];

  aggregate_nodes(tin, rp, csr_s, rsq, hacc, nbase, grp, ln);
  __syncthreads();

  // Segmented reduce: wave w handles rows [w*16, w*16+16), lane = column.
  int c = tid & 63;
  int row0 = (tid >> 6) * 16;
  int cur = gl[row0];
  float run = 0.f;
  for (int rr = 0; rr < 16; rr++) {
    int g = gl[row0 + rr];
    float v = hacc[(row0 + rr) * HS + c];
    if (g != cur) {
      atomicAdd(&r[(size_t)cur * 64 + c], run);
      cur = g;
      run = v;
    } else {
      run += v;
    }
  }
  atomicAdd(&r[(size_t)cur * 64 + c], run);
}

// ---------------- Dense head ----------------
__global__ void __launch_bounds__(256) k_dense1(const float* __restrict__ r,
                                                const float* __restrict__ xa,
                                                const float* __restrict__ W1,
                                                const float* __restrict__ b1,
                                                const float* __restrict__ ob,
                                                float* __restrict__ out,
                                                float* __restrict__ y1T) {
  __shared__ float xs[8 * 72];
  int tid = threadIdx.x;
  int g0 = blockIdx.x * 8;
  if (tid < 8) out[g0 + tid] = ob[0];
  for (int i = tid; i < 8 * 72; i += 256) {
    int g = i / 72, k = i % 72;
    xs[i] = (k < 64) ? r[(size_t)(g0 + g) * 64 + k] : xa[(size_t)(g0 + g) * 8 + (k - 64)];
  }
  __syncthreads();
  float acc[8][2];
#pragma unroll
  for (int g = 0; g < 8; g++) { acc[g][0] = 0.f; acc[g][1] = 0.f; }
  for (int k = 0; k < 72; k++) {
    float w0 = W1[k * 512 + tid];
    float w1 = W1[k * 512 + 256 + tid];
#pragma unroll
    for (int g = 0; g < 8; g++) {
      float xv = xs[g * 72 + k];
      acc[g][0] = fmaf(xv, w0, acc[g][0]);
      acc[g][1] = fmaf(xv, w1, acc[g][1]);
    }
  }
  float bb0 = b1[tid], bb1 = b1[256 + tid];
  float4 v;
  v = make_float4(fmaxf(acc[0][0] + bb0, 0.f), fmaxf(acc[1][0] + bb0, 0.f),
                  fmaxf(acc[2][0] + bb0, 0.f), fmaxf(acc[3][0] + bb0, 0.f));
  *(float4*)&y1T[(size_t)tid * NG + g0] = v;
  v = make_float4(fmaxf(acc[4][0] + bb0, 0.f), fmaxf(acc[5][0] + bb0, 0.f),
                  fmaxf(acc[6][0] + bb0, 0.f), fmaxf(acc[7][0] + bb0, 0.f));
  *(float4*)&y1T[(size_t)tid * NG + g0 + 4] = v;
  v = make_float4(fmaxf(acc[0][1] + bb1, 0.f), fmaxf(acc[1][1] + bb1, 0.f),
                  fmaxf(acc[2][1] + bb1, 0.f), fmaxf(acc[3][1] + bb1, 0.f));
  *(float4*)&y1T[(size_t)(256 + tid) * NG + g0] = v;
  v = make_float4(fmaxf(acc[4][1] + bb1, 0.f), fmaxf(acc[5][1] + bb1, 0.f),
                  fmaxf(acc[6][1] + bb1, 0.f), fmaxf(acc[7][1] + bb1, 0.f));
  *(float4*)&y1T[(size_t)(256 + tid) * NG + g0 + 4] = v;
}

// R22: dense2 = the proven R19 engine (both tiles LDS; 80.8 us, LDS-instr
// floor ~62 us) reverted after R20 (L1-vector W: 88) and R21 (scalar W:
// 125) both regressed. New variable: co-residency. Tile 128g x 64j, 256
// threads, 24.8 KB LDS -> grid 512 = 2 blocks/CU; while one block sits at
// its staging barrier the other's compute feeds the LDS pipe. Same
// micro-tile (8g x 4j), same traffic, same fused-out epilogue.
#define DBK 32
__global__ void __launch_bounds__(256) k_dense2(const float* __restrict__ xT,
                                                const float* __restrict__ W2,
                                                const float* __restrict__ b2,
                                                const float* __restrict__ ow,
                                                float* __restrict__ out) {
  __shared__ float xs[DBK * 128];  // [k][g] 16 KB
  __shared__ float ws[DBK * 64];   // [k][j]  8 KB
  __shared__ float po[128];
  int tid = threadIdx.x;  // 256
  int g0 = (blockIdx.x & 63) * 128;
  int j0 = (blockIdx.x >> 6) * 64;
  int ga = (tid & 15) * 4;   // g offsets {ga..ga+3, 64+ga..64+ga+3}
  int jb = (tid >> 4) * 4;   // j offsets {jb..jb+3}  (16 quads cover 64)

  float acc[4][8];  // [j][g]
#pragma unroll
  for (int jl = 0; jl < 4; jl++) {
    float bb = b2[j0 + jb + jl];
#pragma unroll
    for (int gg = 0; gg < 8; gg++) acc[jl][gg] = bb;
  }

  for (int kb = 0; kb < 512; kb += DBK) {
    __syncthreads();
    // stage x-tile [32k][128g]: 1024 f4, 4/thread
#pragma unroll
    for (int i = 0; i < 4; i++) {
      int f = tid + 256 * i;
      int kr = f >> 5, gc = f & 31;
      ((float4*)xs)[f] = ((const float4*)(xT + (size_t)(kb + kr) * NG + g0))[gc];
    }
    // stage W-tile [32k][64j]: 512 f4, 2/thread
#pragma unroll
    for (int i = 0; i < 2; i++) {
      int f = tid + 256 * i;
      int kr = f >> 4, jc = f & 15;
      ((float4*)ws)[f] = ((const float4*)(W2 + (size_t)(kb + kr) * 512 + j0))[jc];
    }
    __syncthreads();
#pragma unroll 4
    for (int k = 0; k < DBK; k++) {
      float4 x0 = *(const float4*)&xs[k * 128 + ga];
      float4 x1 = *(const float4*)&xs[k * 128 + 64 + ga];
      float4 w0 = *(const float4*)&ws[k * 64 + jb];
      float xv[8] = {x0.x, x0.y, x0.z, x0.w, x1.x, x1.y, x1.z, x1.w};
      float wv[4] = {w0.x, w0.y, w0.z, w0.w};
#pragma unroll
      for (int jj = 0; jj < 4; jj++)
#pragma unroll
        for (int gg = 0; gg < 8; gg++)
          acc[jj][gg] = fmaf(wv[jj], xv[gg], acc[jj][gg]);
    }
  }

  // fused out-epilogue (validated R18)
  if (tid < 128) po[tid] = 0.f;
  __syncthreads();
  float4 owv = *(const float4*)&ow[j0 + jb];
#pragma unroll
  for (int gg = 0; gg < 8; gg++) {
    float pv = fmaxf(acc[0][gg], 0.f) * owv.x + fmaxf(acc[1][gg], 0.f) * owv.y +
               fmaxf(acc[2][gg], 0.f) * owv.z + fmaxf(acc[3][gg], 0.f) * owv.w;
    // lanes l, l^16, l^32, l^48 share the same g (ga depends on tid&15 only)
    pv += __shfl_xor(pv, 16);
    pv += __shfl_xor(pv, 32);
    if ((tid & 48) == 0) {
      int gi = (gg < 4) ? (ga + gg) : (64 + ga + gg - 4);
      atomicAdd(&po[gi], pv);
    }
  }
  __syncthreads();
  if (tid < 128) atomicAdd(&out[g0 + tid], po[tid]);
}

extern "C" void kernel_launch(void* const* d_in, const int* in_sizes, int n_in,
                              void* d_out, int out_size, void* d_ws, size_t ws_size,
                              hipStream_t stream) {
  const float* x_mol    = (const float*)d_in[0];
  const float* x_adduct = (const float*)d_in[1];
  const int*   edge_src = (const int*)d_in[2];
  const int*   edge_dst = (const int*)d_in[3];
  const int*   graph_ids= (const int*)d_in[4];
  const float* gcn_W    = (const float*)d_in[5];
  const float* gcn_b    = (const float*)d_in[6];
  const float* d1W      = (const float*)d_in[7];
  const float* d1b      = (const float*)d_in[8];
  const float* d2W      = (const float*)d_in[9];
  const float* d2b      = (const float*)d_in[10];
  const float* oW       = (const float*)d_in[11];
  const float* obias    = (const float*)d_in[12];
  float* out = (float*)d_out;

  char* p = (char*)d_ws;
  auto alloc = [&](size_t bytes) {
    char* q = p;
    p += (bytes + 255) & ~(size_t)255;
    return q;
  };
  int*   counts   = (int*)alloc((size_t)NN * 4);
  int*   rp       = (int*)alloc((size_t)(NN + 1) * 4);
  int*   bsum     = (int*)alloc(1024 * 4);
  float* rsq      = (float*)alloc((size_t)NN * 4);
  int*   rank     = (int*)alloc((size_t)NE * 4);
  int*   csr_s    = (int*)alloc((size_t)NE * 4);
  uint2* th_a     = (uint2*)alloc((size_t)NN * 64 * 2);  // fp16 t rows (32 MB)
  uint2* th_b     = (uint2*)alloc((size_t)NN * 64 * 2);
  float* r        = (float*)alloc((size_t)NG * 64 * 4);
  float* y1T      = (float*)alloc((size_t)NG * 512 * 4);

  hipMemsetAsync(counts, 0, (size_t)NN * 4, stream);
  hipMemsetAsync(r, 0, (size_t)NG * 64 * 4, stream);
  k_count<<<NE / 256, 256, 0, stream>>>(edge_dst, counts, rank);
  k_scan1<<<NN / 256, 256, 0, stream>>>(counts, rp, bsum);
  k_scan2<<<1, 1024, 0, stream>>>(bsum);
  k_scan3<<<NN / 256, 256, 0, stream>>>(counts, rp, bsum, rsq);
  k_fill<<<8 * (NE / FILL_CHUNK), 256, 0, stream>>>(edge_src, edge_dst, rank, rp, csr_s);

  // t1 = transform(x_mol); t2 = aggT(t1); t3 = aggT(t2); r = aggR(t3)
  k_transform<<<NN / 64, 256, 0, stream>>>(x_mol, gcn_W, gcn_b, rsq, th_a);
  k_aggT<<<NN / 64, 256, 0, stream>>>(th_a, rp, csr_s, rsq,
                                      gcn_W + (size_t)1 * 64 * 64,
                                      gcn_b + (size_t)1 * 64, th_b);
  k_aggT<<<NN / 64, 256, 0, stream>>>(th_b, rp, csr_s, rsq,
                                      gcn_W + (size_t)2 * 64 * 64,
                                      gcn_b + (size_t)2 * 64, th_a);
  k_aggR<<<NN / 64, 256, 0, stream>>>(th_a, rp, csr_s, rsq, graph_ids, r);

  k_dense1<<<NG / 8, 256, 0, stream>>>(r, x_adduct, d1W, d1b, obias, out, y1T);
  k_dense2<<<512, 256, 0, stream>>>(y1T, d2W, d2b, oW, out);
}